// Round 5
// baseline (182.390 us; speedup 1.0000x reference)
//
#include <hip/hip_runtime.h>

typedef float f32x4 __attribute__((ext_vector_type(4)));
typedef short short8 __attribute__((ext_vector_type(8)));
typedef unsigned short ushort8 __attribute__((ext_vector_type(8)));

// ---------------- workspace layout (ushort elements) ----------------
// WTt (3 x [64 ks][128 h][32 c] bf16): 0 .. 786432
// Q  ([8*2048][128] bf16):        786432
// K  ([8*2048][128] bf16):        2883584
// Vt ([8][128][2048] bf16):       4980736
#define WS_Q  786432
#define WS_K  2883584
#define WS_VT 4980736

__device__ __forceinline__ unsigned short f2bf(float x) {
    unsigned u = __float_as_uint(x);
    u += 0x7FFFu + ((u >> 16) & 1u);      // RNE
    return (unsigned short)(u >> 16);
}

__device__ __forceinline__ short8 cvt8(float4 lo, float4 hi) {
    union { unsigned u[4]; short8 s; } r;
    asm("v_cvt_pk_bf16_f32 %0, %1, %2" : "=v"(r.u[0]) : "v"(lo.x), "v"(lo.y));
    asm("v_cvt_pk_bf16_f32 %0, %1, %2" : "=v"(r.u[1]) : "v"(lo.z), "v"(lo.w));
    asm("v_cvt_pk_bf16_f32 %0, %1, %2" : "=v"(r.u[2]) : "v"(hi.x), "v"(hi.y));
    asm("v_cvt_pk_bf16_f32 %0, %1, %2" : "=v"(r.u[3]) : "v"(hi.z), "v"(hi.w));
    return r.s;
}

// swizzle for 128-byte rows (attn P buffer)
__device__ __forceinline__ int swz128(int row, int cbyte) {
    return row * 128 + (cbyte ^ ((row & 7) << 4));
}

// ================= K0: W [2048][128] fp32 -> WTt [64 ks][128 h][32 c] bf16
__global__ __launch_bounds__(256) void wt_kernel(const float* __restrict__ Wq,
        const float* __restrict__ Wk, const float* __restrict__ Wv,
        unsigned short* __restrict__ ws) {
    __shared__ __align__(16) unsigned short tile[64][136];
    int mat = blockIdx.x >> 5, ct = blockIdx.x & 31;
    const float* W = (mat == 0) ? Wq : ((mat == 1) ? Wk : Wv);
    int cbase = ct * 64;
    int tid = threadIdx.x;
#pragma unroll
    for (int p = 0; p < 8; p++) {
        int fidx = p * 256 + tid;          // float4 index, 2048 total
        int row = fidx >> 5;               // c within tile (0..63)
        int c4 = (fidx & 31) << 2;         // h (0..124)
        float4 v = *(const float4*)&W[(size_t)(cbase + row) * 128 + c4];
        tile[row][c4 + 0] = f2bf(v.x);
        tile[row][c4 + 1] = f2bf(v.y);
        tile[row][c4 + 2] = f2bf(v.z);
        tile[row][c4 + 3] = f2bf(v.w);
    }
    __syncthreads();
    int h = tid >> 1, seg = tid & 1;
    unsigned short* dst = ws + mat * 262144 + (ct * 2 + seg) * 4096 + h * 32;
#pragma unroll
    for (int q4 = 0; q4 < 4; q4++) {
        ushort8 pk;
#pragma unroll
        for (int e = 0; e < 8; e++) pk[e] = tile[seg * 32 + q4 * 8 + e][h];
        *(ushort8*)(dst + q4 * 8) = pk;
    }
}

// ================= K1: QKV projection — LDS-free, barrier-free ============
// Wave = independent unit: 32 rows x 128 cols of ONE matrix, K in 64 steps of
// BK=32. A-frags direct from x (fp32->bf16 via cvt_pk), depth-3 registers;
// B-frags direct from L2-resident WTt, depth-2. 16 MFMA/step. No LDS in the
// main loop; the 4 waves of a block share B-frags via L1 (same matrix/step);
// the 3 matrix-siblings of an x-strip are 8 bids apart -> same XCD L2.
__global__ __launch_bounds__(256, 2) void qkv_kernel(const float* __restrict__ x,
        const float* __restrict__ bq, const float* __restrict__ bk,
        const float* __restrict__ bv, unsigned short* __restrict__ ws) {
    __shared__ __align__(16) unsigned short vsm[4][128][36];   // V-transpose only
    int u = blockIdx.x;
    int matrix = (u >> 3) % 3;                    // siblings u, u+8, u+16
    int sg = (u / 24) * 8 + (u & 7);              // 0..127 strip-group (128 rows)
    int tid = threadIdx.x, lane = tid & 63, w = tid >> 6;
    int lr = lane & 15, lg = lane >> 4;
    int mbase = sg * 128 + w * 32;

    const unsigned short* WTt = ws + matrix * 262144;   // [64][128][32]
    const float* bias = (matrix == 0) ? bq : ((matrix == 1) ? bk : bv);
    float bb[8];
#pragma unroll
    for (int nf = 0; nf < 8; nf++) bb[nf] = bias[nf * 16 + lr];

    const float* aP0 = x + (size_t)(mbase + lr) * 2048 + lg * 8;
    const float* aP1 = aP0 + (size_t)16 * 2048;
    const unsigned short* bP = WTt + lr * 32 + lg * 8;

    f32x4 acc[2][8];
#pragma unroll
    for (int i = 0; i < 2; i++)
#pragma unroll
        for (int nf = 0; nf < 8; nf++) acc[i][nf] = (f32x4){0.f, 0.f, 0.f, 0.f};

    float4 A[3][2][2];     // [slot][mfrag][half]
    short8 B[2][8];        // [slot][nfrag]

#define LOADA(S, KS) do { \
        const float* p0_ = aP0 + (size_t)(KS) * 32; \
        const float* p1_ = aP1 + (size_t)(KS) * 32; \
        A[S][0][0] = *(const float4*)p0_;      A[S][0][1] = *(const float4*)(p0_ + 4); \
        A[S][1][0] = *(const float4*)p1_;      A[S][1][1] = *(const float4*)(p1_ + 4); \
    } while (0)
#define LOADB(S, KS) do { \
        const unsigned short* q_ = bP + (size_t)(KS) * 4096; \
        B[S][0] = *(const short8*)(q_);          B[S][1] = *(const short8*)(q_ + 512); \
        B[S][2] = *(const short8*)(q_ + 1024);   B[S][3] = *(const short8*)(q_ + 1536); \
        B[S][4] = *(const short8*)(q_ + 2048);   B[S][5] = *(const short8*)(q_ + 2560); \
        B[S][6] = *(const short8*)(q_ + 3072);   B[S][7] = *(const short8*)(q_ + 3584); \
    } while (0)
#define STEP(SA, SB) do { \
        short8 a0_ = cvt8(A[SA][0][0], A[SA][0][1]); \
        short8 a1_ = cvt8(A[SA][1][0], A[SA][1][1]); \
        _Pragma("unroll") \
        for (int nf_ = 0; nf_ < 8; nf_++) { \
            acc[0][nf_] = __builtin_amdgcn_mfma_f32_16x16x32_bf16(a0_, B[SB][nf_], acc[0][nf_], 0, 0, 0); \
            acc[1][nf_] = __builtin_amdgcn_mfma_f32_16x16x32_bf16(a1_, B[SB][nf_], acc[1][nf_], 0, 0, 0); \
        } \
    } while (0)
    // step s consumes A[s%3], B[s&1]; issues A(s+2), B(s+1) before compute
#define QSTEP(S) do { \
        if ((S) + 2 < 64) LOADA(((S) + 2) % 3, (S) + 2); \
        if ((S) + 1 < 64) LOADB(((S) + 1) & 1, (S) + 1); \
        STEP((S) % 3, (S) & 1); \
    } while (0)

    LOADA(0, 0); LOADA(1, 1); LOADB(0, 0);
    for (int k6 = 0; k6 < 10; k6++) {
        int s0 = k6 * 6;
        QSTEP(s0 + 0); QSTEP(s0 + 1); QSTEP(s0 + 2);
        QSTEP(s0 + 3); QSTEP(s0 + 4); QSTEP(s0 + 5);
    }
    QSTEP(60); QSTEP(61); QSTEP(62); QSTEP(63);
#undef QSTEP
#undef STEP
#undef LOADB
#undef LOADA

    // ----- epilogue -----
    if (matrix < 2) {
        unsigned short* outp = ws + ((matrix == 0) ? WS_Q : WS_K);
        float sc = (matrix == 0) ? 0.08838834764831845f : 1.0f;
#pragma unroll
        for (int i = 0; i < 2; i++)
#pragma unroll
            for (int r = 0; r < 4; r++) {
                size_t t = (size_t)mbase + i * 16 + (lg << 2) + r;
#pragma unroll
                for (int nf = 0; nf < 8; nf++)
                    outp[t * 128 + nf * 16 + lr] = f2bf((acc[i][nf][r] + bb[nf]) * sc);
            }
    } else {
        unsigned short* sm = &vsm[w][0][0];          // [128 h][36]
#pragma unroll
        for (int i = 0; i < 2; i++)
#pragma unroll
            for (int nf = 0; nf < 8; nf++)
#pragma unroll
                for (int r = 0; r < 4; r++)
                    sm[(nf * 16 + lr) * 36 + i * 16 + (lg << 2) + r] =
                        f2bf(acc[i][nf][r] + bb[nf]);
        asm volatile("s_waitcnt lgkmcnt(0)" ::: "memory");   // wave-private region
        int batch = mbase >> 11, tin = mbase & 2047;
        unsigned short* vt = ws + WS_VT + (size_t)batch * 128 * 2048 + tin;
#pragma unroll
        for (int hh = 0; hh < 2; hh++) {
            int h = hh * 64 + lane;
            const unsigned short* src = sm + h * 36;
            unsigned short* dst = vt + (size_t)h * 2048;
#pragma unroll
            for (int e = 0; e < 4; e++)
                *(ushort8*)(dst + e * 8) = *(const ushort8*)(src + e * 8);
        }
    }
}

// ================= K2: causal flash attention (unchanged) =================
__global__ __launch_bounds__(256, 2) void attn_kernel(const unsigned short* __restrict__ ws,
        float* __restrict__ out) {
    __shared__ __align__(16) float o_lds[4][32][128];   // 64 KB
    __shared__ float ml[4][2][32];
    int b = blockIdx.x;
    int qi = 63 - (int)blockIdx.y;          // longest blocks first
    int qbase = qi * 32;
    int tid = threadIdx.x, lane = tid & 63, w = tid >> 6;
    int lr = lane & 15, lg = lane >> 4;
    const unsigned short* Qb = ws + WS_Q + (size_t)b * 2048 * 128;
    const unsigned short* Kb = ws + WS_K + (size_t)b * 2048 * 128;
    const unsigned short* Vt = ws + WS_VT + (size_t)b * 128 * 2048;
    char* p_lds = (char*)&o_lds[w][0][0];   // per-wave private 4 KB

    short8 qf[2][4];
#pragma unroll
    for (int i = 0; i < 2; i++)
#pragma unroll
        for (int kf = 0; kf < 4; kf++)
            qf[i][kf] = *(const short8*)&Qb[(size_t)(qbase + i * 16 + lr) * 128 + kf * 32 + lg * 8];

    f32x4 o[2][8];
#pragma unroll
    for (int i = 0; i < 2; i++)
#pragma unroll
        for (int jn = 0; jn < 8; jn++) o[i][jn] = (f32x4){0.f, 0.f, 0.f, 0.f};
    float mrow[2][4], lrow[2][4];
#pragma unroll
    for (int i = 0; i < 2; i++)
#pragma unroll
        for (int r = 0; r < 4; r++) { mrow[i][r] = -__builtin_inff(); lrow[i][r] = 0.f; }

    int ntiles = qi / 2 + 1;
    for (int ti = w; ti < ntiles; ti += 4) {
        int sb = ti * 64;
        f32x4 s[2][4];
#pragma unroll
        for (int i = 0; i < 2; i++)
#pragma unroll
            for (int nf = 0; nf < 4; nf++) s[i][nf] = (f32x4){0.f, 0.f, 0.f, 0.f};
        {
            short8 kb[4][4];
#pragma unroll
            for (int nf = 0; nf < 4; nf++)
#pragma unroll
                for (int kf = 0; kf < 4; kf++)
                    kb[nf][kf] = *(const short8*)&Kb[(size_t)(sb + nf * 16 + lr) * 128 + kf * 32 + lg * 8];
#pragma unroll
            for (int kf = 0; kf < 4; kf++)
#pragma unroll
                for (int i = 0; i < 2; i++)
#pragma unroll
                    for (int nf = 0; nf < 4; nf++)
                        s[i][nf] = __builtin_amdgcn_mfma_f32_16x16x32_bf16(qf[i][kf], kb[nf][kf], s[i][nf], 0, 0, 0);
        }
        if (sb + 63 > qbase) {   // diagonal tile(s): causal mask
#pragma unroll
            for (int i = 0; i < 2; i++)
#pragma unroll
                for (int nf = 0; nf < 4; nf++)
#pragma unroll
                    for (int r = 0; r < 4; r++) {
                        int sg = sb + nf * 16 + lr;
                        int qg = qbase + i * 16 + (lg << 2) + r;
                        if (sg > qg) s[i][nf][r] = -__builtin_inff();
                    }
        }
        float alpha[2][4];
#pragma unroll
        for (int i = 0; i < 2; i++)
#pragma unroll
            for (int r = 0; r < 4; r++) {
                float pm = fmaxf(fmaxf(s[i][0][r], s[i][1][r]), fmaxf(s[i][2][r], s[i][3][r]));
                pm = fmaxf(pm, __shfl_xor(pm, 1));
                pm = fmaxf(pm, __shfl_xor(pm, 2));
                pm = fmaxf(pm, __shfl_xor(pm, 4));
                pm = fmaxf(pm, __shfl_xor(pm, 8));
                float mn = fmaxf(mrow[i][r], pm);
                alpha[i][r] = __expf(mrow[i][r] - mn);
                mrow[i][r] = mn;
            }
#pragma unroll
        for (int i = 0; i < 2; i++)
#pragma unroll
            for (int r = 0; r < 4; r++) {
                float rs = 0.f;
#pragma unroll
                for (int nf = 0; nf < 4; nf++) {
                    float p = __expf(s[i][nf][r] - mrow[i][r]);
                    s[i][nf][r] = p;
                    rs += p;
                }
                rs += __shfl_xor(rs, 1);
                rs += __shfl_xor(rs, 2);
                rs += __shfl_xor(rs, 4);
                rs += __shfl_xor(rs, 8);
                lrow[i][r] = lrow[i][r] * alpha[i][r] + rs;
            }
#pragma unroll
        for (int i = 0; i < 2; i++)
#pragma unroll
            for (int jn = 0; jn < 8; jn++)
#pragma unroll
                for (int r = 0; r < 4; r++) o[i][jn][r] *= alpha[i][r];
#pragma unroll
        for (int i = 0; i < 2; i++)
#pragma unroll
            for (int nf = 0; nf < 4; nf++)
#pragma unroll
                for (int r = 0; r < 4; r++) {
                    int row = i * 16 + (lg << 2) + r;
                    int cb2 = (nf * 16 + lr) * 2;
                    *(unsigned short*)(p_lds + swz128(row, cb2)) = f2bf(s[i][nf][r]);
                }
        asm volatile("s_waitcnt lgkmcnt(0)" ::: "memory");
        short8 pa[2][2];
#pragma unroll
        for (int i = 0; i < 2; i++)
#pragma unroll
            for (int kf = 0; kf < 2; kf++)
                pa[i][kf] = *(const short8*)(p_lds + swz128(i * 16 + lr, kf * 64 + lg * 16));
        short8 vb[8][2];
#pragma unroll
        for (int nf = 0; nf < 8; nf++)
#pragma unroll
            for (int kf = 0; kf < 2; kf++)
                vb[nf][kf] = *(const short8*)&Vt[(size_t)(nf * 16 + lr) * 2048 + sb + kf * 32 + lg * 8];
#pragma unroll
        for (int i = 0; i < 2; i++)
#pragma unroll
            for (int nf = 0; nf < 8; nf++)
#pragma unroll
                for (int kf = 0; kf < 2; kf++)
                    o[i][nf] = __builtin_amdgcn_mfma_f32_16x16x32_bf16(pa[i][kf], vb[nf][kf], o[i][nf], 0, 0, 0);
    }
#pragma unroll
    for (int i = 0; i < 2; i++)
#pragma unroll
        for (int r = 0; r < 4; r++) {
            int q = i * 16 + (lg << 2) + r;
            ml[w][0][q] = mrow[i][r];
            ml[w][1][q] = lrow[i][r];
        }
    asm volatile("s_waitcnt lgkmcnt(0)" ::: "memory");
#pragma unroll
    for (int i = 0; i < 2; i++)
#pragma unroll
        for (int jn = 0; jn < 8; jn++)
#pragma unroll
            for (int r = 0; r < 4; r++)
                o_lds[w][i * 16 + (lg << 2) + r][jn * 16 + lr] = o[i][jn][r];
    __syncthreads();
    int q = tid >> 3, h0 = (tid & 7) << 4;
    float mg = fmaxf(fmaxf(ml[0][0][q], ml[1][0][q]), fmaxf(ml[2][0][q], ml[3][0][q]));
    float scw[4], den = 0.f;
#pragma unroll
    for (int w4 = 0; w4 < 4; w4++) {
        scw[w4] = __expf(ml[w4][0][q] - mg);
        den += scw[w4] * ml[w4][1][q];
    }
    float inv = 1.0f / den;
    float* op = out + ((size_t)b * 2048 + qbase + q) * 128 + h0;
#pragma unroll
    for (int jj = 0; jj < 4; jj++) {
        f32x4 a4 = (f32x4){0.f, 0.f, 0.f, 0.f};
#pragma unroll
        for (int w4 = 0; w4 < 4; w4++) {
            f32x4 v = *(const f32x4*)&o_lds[w4][q][h0 + jj * 4];
            a4 += scw[w4] * v;
        }
        a4 *= inv;
        *(f32x4*)(op + jj * 4) = a4;
    }
}

extern "C" void kernel_launch(void* const* d_in, const int* in_sizes, int n_in,
                              void* d_out, int out_size, void* d_ws, size_t ws_size,
                              hipStream_t stream) {
    (void)in_sizes; (void)n_in; (void)out_size; (void)ws_size;
    const float* x  = (const float*)d_in[0];
    const float* Wq = (const float*)d_in[1];
    const float* bq = (const float*)d_in[2];
    const float* Wk = (const float*)d_in[3];
    const float* bk = (const float*)d_in[4];
    const float* Wv = (const float*)d_in[5];
    const float* bv = (const float*)d_in[6];
    unsigned short* ws = (unsigned short*)d_ws;
    float* out = (float*)d_out;

    wt_kernel<<<96, 256, 0, stream>>>(Wq, Wk, Wv, ws);
    qkv_kernel<<<384, 256, 0, stream>>>(x, bq, bk, bv, ws);
    attn_kernel<<<dim3(8, 64), 256, 0, stream>>>(ws, out);
}